// Round 13
// baseline (146.742 us; speedup 1.0000x reference)
//
#include <hip/hip_runtime.h>
#include <hip/hip_bf16.h>

// Problem dims (fixed by reference setup)
#define B_   16
#define N_   8
#define C_   512
#define D_   768
#define HH   64
#define WW   64
#define HW   4096          // 64*64 pixels per batch

typedef __bf16 bf16;
typedef __attribute__((ext_vector_type(8))) __bf16 bf16x8;
typedef __attribute__((ext_vector_type(4))) __bf16 bf16x4;
typedef __attribute__((ext_vector_type(4))) float  f32x4;

// ---------------------------------------------------------------------------
// K_pre (single launch) — unchanged from R12.
// Blocks 0..127  : (b,n): Q in-register -> Ql LDS; Qkf in MFMA-fragment order.
// Blocks 128..639: W2f = wo_w·wv_w in fragment order; b2.
__global__ __launch_bounds__(512) void k_pre(const float* __restrict__ se,
                                             const float* __restrict__ weights,
                                             const float* __restrict__ wq_w,
                                             const float* __restrict__ wq_b,
                                             const float* __restrict__ wk_w,
                                             const float* __restrict__ wo_w,
                                             const float* __restrict__ wv_w,
                                             const float* __restrict__ wv_b,
                                             bf16* __restrict__ Qkf,
                                             bf16* __restrict__ W2f,
                                             float* __restrict__ b2) {
    __shared__ __align__(16) unsigned char smem[12288];
    int tid = threadIdx.x;
    int blk = blockIdx.x;
    if (blk < 128) {
        int b = blk >> 3, n = blk & 7;
        float* we = (float*)smem;                     // [768]
        float* Ql = (float*)(smem + 3072);            // [512]
        float wt = weights[n];
        const float* se_row = se + (size_t)(b * N_ + n) * D_;
        for (int i = tid; i < D_; i += 512) we[i] = se_row[i] * wt;
        __syncthreads();
        int wid = tid >> 6, lane = tid & 63;
        f32x4 wer[3];
        #pragma unroll
        for (int k = 0; k < 3; ++k)
            wer[k] = *(const f32x4*)(we + k * 256 + lane * 4);
        int c0 = wid * 64;
        #pragma unroll 2
        for (int cc = 0; cc < 64; ++cc) {
            int c = c0 + cc;
            const float* row = wq_w + (size_t)c * D_ + lane * 4;
            float dot = 0.f;
            #pragma unroll
            for (int k = 0; k < 3; ++k) {
                f32x4 v = *(const f32x4*)(row + k * 256);
                dot += v[0]*wer[k][0] + v[1]*wer[k][1]
                     + v[2]*wer[k][2] + v[3]*wer[k][3];
            }
            #pragma unroll
            for (int off = 1; off <= 32; off <<= 1) dot += __shfl_xor(dot, off);
            if (lane == 0) Ql[c] = dot + wq_b[c];
        }
        __syncthreads();
        int m = tid;
        float a0 = 0.f, a1 = 0.f, a2 = 0.f, a3 = 0.f;
        #pragma unroll 2
        for (int o = 0; o < C_; o += 4) {
            a0 = fmaf(Ql[o + 0], wk_w[(size_t)(o + 0) * C_ + m], a0);
            a1 = fmaf(Ql[o + 1], wk_w[(size_t)(o + 1) * C_ + m], a1);
            a2 = fmaf(Ql[o + 2], wk_w[(size_t)(o + 2) * C_ + m], a2);
            a3 = fmaf(Ql[o + 3], wk_w[(size_t)(o + 3) * C_ + m], a3);
        }
        float val = ((a0 + a1) + (a2 + a3)) * 3.6084391824351615e-2f;
        int t = m >> 5, sl = (m >> 3) & 3, el = m & 7;
        size_t qb = (size_t)b * 8192 + (size_t)t * 512;
        Qkf[qb + (size_t)(n | (sl << 4)) * 8 + el]       = (bf16)val;
        Qkf[qb + (size_t)((n + 8) | (sl << 4)) * 8 + el] = (bf16)0.f;
    } else {
        int bb = blk - 128;                           // 0..511
        int og = bb >> 3, cc = bb & 7;
        int cl = tid & 63, kq = tid >> 6;
        int kqq = kq & 3;
        int khalf = kq >> 2;
        int c  = cc * 64 + cl;
        const float* wo = wo_w + (size_t)og * 8 * C_;
        float a[8] = {};
        #pragma unroll 4
        for (int i = 0; i < 64; ++i) {
            int k = kqq * 128 + khalf * 64 + i;
            float v = wv_w[(size_t)k * C_ + c];
            #pragma unroll
            for (int j = 0; j < 8; ++j)
                a[j] = fmaf(wo[(size_t)j * C_ + k], v, a[j]);
        }
        float (*part)[8][64] = (float(*)[8][64])smem;
        #pragma unroll
        for (int j = 0; j < 8; ++j) {
            if (khalf) part[kqq][j][cl] = a[j];
        }
        __syncthreads();
        if (khalf == 0) {
            #pragma unroll
            for (int j = 0; j < 8; ++j) part[kqq][j][cl] += a[j];
        }
        __syncthreads();
        if (kq == 0) {
            int t  = c >> 5;
            int ln = (((c >> 3) & 3) << 4);
            int el = c & 7;
            #pragma unroll
            for (int j = 0; j < 8; ++j) {
                float s = part[0][j][cl] + part[1][j][cl]
                        + part[2][j][cl] + part[3][j][cl];
                int o = og * 8 + j;
                W2f[(size_t)t * 16384 + (o >> 7) * 4096 + ((o >> 4) & 7) * 512
                    + (size_t)((o & 15) | ln) * 8 + el] = (bf16)s;
            }
        }
        if (cc == 0 && tid < 8) {
            float sb = 0.f;
            const float* rr = wo_w + (size_t)(og * 8 + tid) * C_;
            #pragma unroll 4
            for (int m = 0; m < C_; ++m) sb = fmaf(rr[m], wv_b[m], sb);
            b2[og * 8 + tid] = sb;
        }
    }
}

// ---------------------------------------------------------------------------
// K2 (fused v7, two-phase): per block (b, pt): full-M GEMM over 128-px panel.
//   PHASE 1: bulk-stage Bp[128 p][512 c] (128KB, swz) with a 4-deep static
//            register pipeline (32 loads in flight/thread); ONE barrier.
//   PHASE 2: 16 tiles of {A-frags from L2 (fragment-order W2f), 4 ds_read,
//            36 MFMA} with ZERO barriers — waves drift, SIMD pair covers
//            latency, MFMA issues back-to-back.
//   Then in-register softmax + epilogue (residual from Bp).
__global__ __launch_bounds__(512, 2) void k_fused(const float* __restrict__ x,
                                                  const bf16* __restrict__ W2f,
                                                  const float* __restrict__ b2,
                                                  const float* __restrict__ wo_b,
                                                  const bf16* __restrict__ Qkf,
                                                  float* __restrict__ out) {
    // XCD swizzle (512 % 8 == 0 -> bijective)
    int id = blockIdx.x;
    int job = (id & 7) * 64 + (id >> 3);          // 0..511
    int b = job >> 5, pt = job & 31;
    int p0 = pt * 128;                            // 2 complete h-rows

    __shared__ __align__(128) unsigned char Bp[131072]; // [128 p][512 c] bf16 swz
    __shared__ float s_lds[128];

    int tid = threadIdx.x;
    int wid = tid >> 6, lane = tid & 63;
    int wm = wid >> 1, wp = wid & 1;

    int pg = tid & 127, cg = tid >> 7;            // B-stage: pixel, c-octet
    int fB = (pg & 63) << 4;

    f32x4 acc[8][4] = {};
    f32x4 acc_q[4] = {};

    const float* xb = x + (size_t)b * C_ * HW + p0 + pg;
    const bf16* Wb  = W2f + wm * 4096 + (size_t)lane * 8;
    const bf16* Qb  = Qkf + (size_t)b * 8192 + (size_t)lane * 8;

#define IB(T, BV)                                                             \
    { _Pragma("unroll")                                                       \
      for (int i = 0; i < 8; ++i)                                            \
          BV[i] = xb[(size_t)((T)*32 + cg*8 + i) * HW]; }

#define SW(T, BV)                                                             \
    { bf16x8 bw;                                                              \
      _Pragma("unroll")                                                       \
      for (int i = 0; i < 8; ++i) bw[i] = (bf16)BV[i];                        \
      *(bf16x8*)(&Bp[pg*1024 + ((((T)*64) + cg*16) ^ fB)]) = bw; }

#define IA(T)                                                                 \
    { _Pragma("unroll")                                                       \
      for (int i = 0; i < 8; ++i)                                            \
          av[i] = *(const bf16x8*)(Wb + (size_t)(T)*16384 + i*512);           \
      if (wm == 0) aq = *(const bf16x8*)(Qb + (size_t)(T)*512); }

#define MT(T)                                                                 \
    { int kb = (T)*64 + ((lane>>4)<<4);                                       \
      bf16x8 bbf[4];                                                          \
      _Pragma("unroll")                                                       \
      for (int j = 0; j < 4; ++j) {                                          \
          int row = wp*64 + j*16 + (lane&15);                                 \
          bbf[j] = *(const bf16x8*)(&Bp[row*1024 + (kb ^ ((row&63)<<4))]);    \
      }                                                                       \
      __builtin_amdgcn_s_setprio(1);                                          \
      _Pragma("unroll")                                                       \
      for (int i = 0; i < 8; ++i)                                            \
          _Pragma("unroll")                                                   \
          for (int j = 0; j < 4; ++j)                                        \
              acc[i][j] = __builtin_amdgcn_mfma_f32_16x16x32_bf16(            \
                              av[i], bbf[j], acc[i][j], 0, 0, 0);             \
      if (wm == 0) {                                                          \
          _Pragma("unroll")                                                   \
          for (int j = 0; j < 4; ++j)                                        \
              acc_q[j] = __builtin_amdgcn_mfma_f32_16x16x32_bf16(             \
                             aq, bbf[j], acc_q[j], 0, 0, 0);                  \
      }                                                                       \
      __builtin_amdgcn_s_setprio(0); }

    // ---- PHASE 1: bulk-stage Bp, 4-deep static pipeline ----
    {
        float v0[8], v1[8], v2[8], v3[8];
        IB(0, v0); IB(1, v1); IB(2, v2); IB(3, v3);
        #pragma unroll 1
        for (int base = 0; base < 12; base += 4) {
            SW(base + 0, v0); IB(base + 4, v0);
            SW(base + 1, v1); IB(base + 5, v1);
            SW(base + 2, v2); IB(base + 6, v2);
            SW(base + 3, v3); IB(base + 7, v3);
        }
        SW(12, v0); SW(13, v1); SW(14, v2); SW(15, v3);
    }
    __syncthreads();                              // Bp fully staged (only barrier)

    // ---- PHASE 2: 16 tiles, NO barriers ----
    {
        bf16x8 av[8];
        bf16x8 aq = {};
        #pragma unroll 1
        for (int t = 0; t < 16; ++t) {
            IA(t);
            MT(t);
        }
    }

    // ---- in-register softmax over w (64 px) on waves 0,1 ----
    if (wm == 0) {
        float sm[4];
        #pragma unroll
        for (int r = 0; r < 4; ++r) {
            float m = fmaxf(fmaxf(acc_q[0][r], acc_q[1][r]),
                            fmaxf(acc_q[2][r], acc_q[3][r]));
            #pragma unroll
            for (int off = 1; off <= 8; off <<= 1) m = fmaxf(m, __shfl_xor(m, off));
            float s = 0.f;
            #pragma unroll
            for (int j = 0; j < 4; ++j) { acc_q[j][r] = __expf(acc_q[j][r] - m); s += acc_q[j][r]; }
            #pragma unroll
            for (int off = 1; off <= 8; off <<= 1) s += __shfl_xor(s, off);
            sm[r] = s;
        }
        f32x4 rcp;
        #pragma unroll
        for (int r = 0; r < 4; ++r) rcp[r] = 1.f / sm[r];
        #pragma unroll
        for (int j = 0; j < 4; ++j) {
            float sp = acc_q[j][0]*rcp[0] + acc_q[j][1]*rcp[1]
                     + acc_q[j][2]*rcp[2] + acc_q[j][3]*rcp[3];
            sp += __shfl_xor(sp, 16);             // add the other n-quad
            if (lane < 16) s_lds[wp*64 + j*16 + lane] = sp;
        }
    }
    __syncthreads();

    // ---- epilogue: out = bf16(x) + wo_b + s*(acc + b2); residual from Bp ----
    int r4 = (lane >> 4) << 2;
    int cl = lane & 15;
    #pragma unroll
    for (int j = 0; j < 4; ++j) {
        int pl = wp * 64 + j * 16 + cl;
        float sv = s_lds[pl];
        int fBp = (pl & 63) << 4;
        #pragma unroll
        for (int i = 0; i < 8; ++i) {
            int ob = wm * 128 + i * 16 + r4;
            f32x4 b2v = *(const f32x4*)(b2 + ob);
            f32x4 wbv = *(const f32x4*)(wo_b + ob);
            bf16x4 rx = *(const bf16x4*)(&Bp[pl*1024 + ((ob*2) ^ fBp)]);
            #pragma unroll
            for (int r = 0; r < 4; ++r) {
                size_t gi = ((size_t)b * C_ + ob + r) * HW + p0 + pl;
                out[gi] = (float)rx[r] + wbv[r] + sv * (acc[i][j][r] + b2v[r]);
            }
        }
    }
#undef IB
#undef SW
#undef IA
#undef MT
}

// ---------------------------------------------------------------------------
extern "C" void kernel_launch(void* const* d_in, const int* in_sizes, int n_in,
                              void* d_out, int out_size, void* d_ws, size_t ws_size,
                              hipStream_t stream) {
    const float* x    = (const float*)d_in[0];
    const float* se   = (const float*)d_in[1];
    const float* wts  = (const float*)d_in[2];
    const float* wq_w = (const float*)d_in[3];
    const float* wq_b = (const float*)d_in[4];
    const float* wk_w = (const float*)d_in[5];
    // d_in[6] = wk_b: constant over softmax axis -> cancels, unused
    const float* wv_w = (const float*)d_in[7];
    const float* wv_b = (const float*)d_in[8];
    const float* wo_w = (const float*)d_in[9];
    const float* wo_b = (const float*)d_in[10];
    float* out = (float*)d_out;

    // workspace layout (<1MB)
    char* ws = (char*)d_ws;
    bf16*  Qkf = (bf16*) (ws + 0);          // 256KB [16 b][16 t][64 lane][8] frag-order
    bf16*  W2f = (bf16*) (ws + 262144);     // 512KB [16 t][4 wm][8 i][64 lane][8]
    float* b2  = (float*)(ws + 786432);     // 2KB

    k_pre   <<<dim3(640), dim3(512), 0, stream>>>(se, wts, wq_w, wq_b, wk_w,
                                                  wo_w, wv_w, wv_b, Qkf, W2f, b2);
    k_fused <<<dim3(512), dim3(512), 0, stream>>>(x, W2f, b2, wo_b, Qkf, out);
}